// Round 6
// baseline (179.856 us; speedup 1.0000x reference)
//
#include <hip/hip_runtime.h>
#include <hip/hip_bf16.h>

#define Bn  16
#define Cn  256
#define CKn 32
#define Nn  2304   // 48*48

typedef __attribute__((ext_vector_type(16))) float f32x16;
typedef __attribute__((ext_vector_type(8)))  short bf16x8;

union FragU { unsigned u[4]; bf16x8 v; };

__device__ __forceinline__ unsigned pk(float lo, float hi){
  unsigned a = (unsigned)__bfloat16_as_ushort(__float2bfloat16(lo));
  unsigned b = (unsigned)__bfloat16_as_ushort(__float2bfloat16(hi));
  return a | (b << 16);
}

// D-layout (col=lane&31, row=(r&3)+8*(r>>2)+4h) -> A/B-frag layout (row/col=lane&31,
// k=8h+e). Outputs: w0 (k-pair 16kt+8h), w2 (k-pair 16kt+8h+4).
__device__ __forceinline__ void halfswap(unsigned A, unsigned Bv, int h,
                                         unsigned &w0, unsigned &w2){
  unsigned As = (unsigned)__shfl_xor((int)A, 32);
  unsigned Bs = (unsigned)__shfl_xor((int)Bv, 32);
  w0 = h ? Bs : A;
  w2 = h ? Bv : As;
}

__device__ __forceinline__ void conv_store(const f32x16& a, int h, int l,
                                           __hip_bfloat16* dst0, size_t stride){
  unsigned Wp[8];
  #pragma unroll
  for (int q = 0; q < 8; ++q) Wp[q] = pk(a[2*q], a[2*q+1]);
  #pragma unroll
  for (int k2 = 0; k2 < 2; ++k2){
    FragU u;
    halfswap(Wp[4*k2+0], Wp[4*k2+2], h, u.u[0], u.u[2]);
    halfswap(Wp[4*k2+1], Wp[4*k2+3], h, u.u[1], u.u[3]);
    *(bf16x8*)(dst0 + k2*stride + l*8) = u.v;
  }
}

// async global -> LDS, 16B per lane
__device__ __forceinline__ void gld16(const void* g, void* l){
  __builtin_amdgcn_global_load_lds(
      (__attribute__((address_space(1))) void*)const_cast<void*>(g),
      (__attribute__((address_space(3))) void*)l, 16, 0, 0);
}

// ---------------------------------------------------------------------------
// Pack weights+bias into MFMA frag layout. Wf[kt 0..16][tile 0..9][512] bf16.
// ---------------------------------------------------------------------------
__global__ __launch_bounds__(64) void wfrag_kernel(
    const float* __restrict__ Wq, const float* __restrict__ bq,
    const float* __restrict__ Wk, const float* __restrict__ bk,
    const float* __restrict__ Wv, const float* __restrict__ bv,
    __hip_bfloat16* __restrict__ Wf){
  const int kt = blockIdx.x / 10, tile = blockIdx.x % 10;
  const int l = threadIdx.x, lo = l & 31, h = l >> 5;
  __hip_bfloat16* dst = Wf + (size_t)(kt*10 + tile)*512 + l*8;
  if (kt < 16){
    const float* Wp; int row;
    if (tile < 8)       { Wp = Wv; row = tile*32 + lo; }
    else if (tile == 8) { Wp = Wq; row = lo; }
    else                { Wp = Wk; row = lo; }
    #pragma unroll
    for (int e = 0; e < 8; ++e)
      dst[e] = __float2bfloat16(Wp[(size_t)row*Cn + kt*16 + 8*h + e]);
  } else {
    const float* bp = tile < 8 ? bv : (tile == 8 ? bq : bk);
    int row = tile < 8 ? tile*32 + lo : lo;
    #pragma unroll
    for (int e = 0; e < 8; ++e)
      dst[e] = __float2bfloat16((h == 0 && e == 0) ? bp[row] : 0.f);
  }
}

// ---------------------------------------------------------------------------
// Projection GEMM. Q is pre-scaled by log2(e)/sqrt(C).
// ---------------------------------------------------------------------------
__global__ __launch_bounds__(256) void proj_kernel(
    const float* __restrict__ x, const __hip_bfloat16* __restrict__ Wf,
    __hip_bfloat16* __restrict__ Qf, __hip_bfloat16* __restrict__ Kf,
    __hip_bfloat16* __restrict__ Vf){
  const int u = blockIdx.x*4 + (threadIdx.x >> 6);
  const int b = u / 72, n32 = u % 72;
  const int l = threadIdx.x & 63, lo = l & 31, h = l >> 5;
  const int n0 = n32*32;

  f32x16 acc[10];
  #pragma unroll
  for (int t = 0; t < 10; ++t)
    #pragma unroll
    for (int r = 0; r < 16; ++r) acc[t][r] = 0.f;

  const float* xb = x + (size_t)b*Cn*Nn + n0 + lo;

  #pragma unroll 1
  for (int kt = 0; kt < 16; ++kt){
    FragU xf;
    float v[8];
    #pragma unroll
    for (int e = 0; e < 8; ++e) v[e] = xb[(size_t)(kt*16 + 8*h + e)*Nn];
    #pragma unroll
    for (int q = 0; q < 4; ++q) xf.u[q] = pk(v[2*q], v[2*q+1]);
    const __hip_bfloat16* wfp = Wf + (size_t)(kt*10)*512 + l*8;
    #pragma unroll
    for (int t = 0; t < 10; ++t){
      bf16x8 wf = *(const bf16x8*)(wfp + t*512);
      if (t < 8) acc[t] = __builtin_amdgcn_mfma_f32_32x32x16_bf16(xf.v, wf, acc[t], 0,0,0);
      else       acc[t] = __builtin_amdgcn_mfma_f32_32x32x16_bf16(wf, xf.v, acc[t], 0,0,0);
    }
  }
  { // bias k-step
    FragU xf;
    xf.u[0] = h ? 0u : 0x00003f80u;
    xf.u[1] = xf.u[2] = xf.u[3] = 0u;
    const __hip_bfloat16* wfp = Wf + (size_t)(16*10)*512 + l*8;
    #pragma unroll
    for (int t = 0; t < 10; ++t){
      bf16x8 wf = *(const bf16x8*)(wfp + t*512);
      if (t < 8) acc[t] = __builtin_amdgcn_mfma_f32_32x32x16_bf16(xf.v, wf, acc[t], 0,0,0);
      else       acc[t] = __builtin_amdgcn_mfma_f32_32x32x16_bf16(wf, xf.v, acc[t], 0,0,0);
    }
  }

  // fold softmax scale into Q: k1 = log2(e)/sqrt(256)
  #pragma unroll
  for (int r = 0; r < 16; ++r) acc[8][r] *= 0.09016844f;

  #pragma unroll
  for (int t = 0; t < 8; ++t)
    conv_store(acc[t], h, l, Vf + (((size_t)b*144 + n32*2)*8 + t)*512, 8*512);
  conv_store(acc[8], h, l, Qf + ((size_t)b*72 + n32)*2*512, 512);
  conv_store(acc[9], h, l, Kf + ((size_t)b*72 + n32)*2*512, 512);
}

// ---------------------------------------------------------------------------
// Attention: block = (b, 64 q-rows), 4 waves = 2 wq x 2 wc. All waves sweep
// the SAME jt; V+K double-buffered in LDS via global_load_lds with counted
// vmcnt(9) (never 0 in-loop) + raw s_barrier (T3-lite 2-phase). acc = 64 AGPR
// (32q x 128c per wave). No cross-wave merge; direct coalesced epilogue.
// ---------------------------------------------------------------------------
__global__ __launch_bounds__(256, 2) void attn_kernel(
    const __hip_bfloat16* __restrict__ Qf, const __hip_bfloat16* __restrict__ Kf,
    const __hip_bfloat16* __restrict__ Vf, const float* __restrict__ x,
    const float* __restrict__ gptr, float* __restrict__ out){
  __shared__ __align__(16) char smem[77824];   // 2 x 36864 (V32K+K4K) + 4096 (Q)
  const int xcd = blockIdx.x & 7, seq = blockIdx.x >> 3;   // 576 = 8*72
  const int b   = xcd*2 + (seq / 36);                      // 2 batches per XCD
  const int i64 = seq % 36;
  const int tid = threadIdx.x;
  const int w = tid >> 6, l = tid & 63, lo = l & 31, h = l >> 5;
  const int wq = w >> 1, wc = w & 1;

  // stage one 36KB tile: 8 V rounds + 1 K round (9 vm-ops/thread)
  auto stage = [&](int jt, int buf){
    const char* gV = (const char*)Vf + ((size_t)(b*1152 + jt*32))*1024 + tid*16;
    char* lV = smem + buf*36864 + w*1024;
    #pragma unroll
    for (int r = 0; r < 8; ++r)
      gld16(gV + r*4096, lV + r*4096);
    const char* gK = (const char*)Kf + ((size_t)(b*144 + jt*4))*1024 + tid*16;
    gld16(gK, smem + buf*36864 + 32768 + w*1024);
  };

  // prologue: stage Q (1 round) then tile 0
  {
    const char* gQ = (const char*)Qf + ((size_t)(b*144 + i64*4))*1024 + tid*16;
    gld16(gQ, smem + 73728 + w*1024);
  }
  stage(0, 0);
  asm volatile("s_waitcnt vmcnt(9)" ::: "memory");   // Q landed (tile0 may fly)
  __builtin_amdgcn_s_barrier();
  __builtin_amdgcn_sched_barrier(0);

  bf16x8 qf[2];
  #pragma unroll
  for (int kt = 0; kt < 2; ++kt)
    qf[kt] = *(const bf16x8*)(smem + 73728 + (wq*2 + kt)*1024 + l*16);

  f32x16 acc[4];
  #pragma unroll
  for (int c = 0; c < 4; ++c)
    #pragma unroll
    for (int r = 0; r < 16; ++r) acc[c][r] = 0.f;
  float m = -3.0e38f, lsum = 0.f;

  #pragma unroll 1
  for (int jt = 0; jt < 36; ++jt){
    const int cur = jt & 1;
    int jtn = jt + 1; if (jtn == 36) jtn = 0;   // wrap-stage keeps vmcnt uniform
    stage(jtn, cur ^ 1);
    asm volatile("s_waitcnt vmcnt(9)" ::: "memory");  // tile jt landed; jt+1 in flight
    __builtin_amdgcn_s_barrier();
    __builtin_amdgcn_sched_barrier(0);

    const char* cb = smem + cur*36864;
    bf16x8 kf[2][2];
    #pragma unroll
    for (int js = 0; js < 2; ++js)
      #pragma unroll
      for (int kt = 0; kt < 2; ++kt)
        kf[js][kt] = *(const bf16x8*)(cb + 32768 + (js*2 + kt)*1024 + l*16);

    f32x16 z;
    #pragma unroll
    for (int r = 0; r < 16; ++r) z[r] = 0.f;
    f32x16 S0 = __builtin_amdgcn_mfma_f32_32x32x16_bf16(kf[0][0], qf[0], z, 0,0,0);
    S0 = __builtin_amdgcn_mfma_f32_32x32x16_bf16(kf[0][1], qf[1], S0, 0,0,0);
    f32x16 S1 = __builtin_amdgcn_mfma_f32_32x32x16_bf16(kf[1][0], qf[0], z, 0,0,0);
    S1 = __builtin_amdgcn_mfma_f32_32x32x16_bf16(kf[1][1], qf[1], S1, 0,0,0);

    // tree max (S already in log2 domain via pre-scaled Q)
    float tm[16];
    #pragma unroll
    for (int r = 0; r < 16; ++r) tm[r] = fmaxf(S0[r], S1[r]);
    #pragma unroll
    for (int s = 8; s > 0; s >>= 1)
      #pragma unroll
      for (int r = 0; r < s; ++r) tm[r] = fmaxf(tm[r], tm[r+s]);
    float mloc = fmaxf(tm[0], __shfl_xor(tm[0], 32));
    if (__any(mloc > m + 8.f)){          // defer-max
      float mnew = fmaxf(m, mloc);
      float f = exp2f(m - mnew);
      lsum *= f;
      #pragma unroll
      for (int c = 0; c < 4; ++c)
        #pragma unroll
        for (int r = 0; r < 16; ++r) acc[c][r] *= f;
      m = mnew;
    }

    FragU pf[4];
    float sadd0 = 0.f, sadd1 = 0.f;
    {
      unsigned Wp[8];
      #pragma unroll
      for (int q = 0; q < 8; ++q){
        float p0 = exp2f(S0[2*q]   - m);
        float p1 = exp2f(S0[2*q+1] - m);
        sadd0 += p0 + p1; Wp[q] = pk(p0, p1);
      }
      halfswap(Wp[0], Wp[2], h, pf[0].u[0], pf[0].u[2]);
      halfswap(Wp[1], Wp[3], h, pf[0].u[1], pf[0].u[3]);
      halfswap(Wp[4], Wp[6], h, pf[1].u[0], pf[1].u[2]);
      halfswap(Wp[5], Wp[7], h, pf[1].u[1], pf[1].u[3]);
    }
    {
      unsigned Wp[8];
      #pragma unroll
      for (int q = 0; q < 8; ++q){
        float p0 = exp2f(S1[2*q]   - m);
        float p1 = exp2f(S1[2*q+1] - m);
        sadd1 += p0 + p1; Wp[q] = pk(p0, p1);
      }
      halfswap(Wp[0], Wp[2], h, pf[2].u[0], pf[2].u[2]);
      halfswap(Wp[1], Wp[3], h, pf[2].u[1], pf[2].u[3]);
      halfswap(Wp[4], Wp[6], h, pf[3].u[0], pf[3].u[2]);
      halfswap(Wp[5], Wp[7], h, pf[3].u[1], pf[3].u[3]);
    }
    lsum += sadd0 + sadd1;

    // PV from LDS: this wave's 128-channel half (ct = wc*4 + c)
    #pragma unroll
    for (int js = 0; js < 4; ++js){
      #pragma unroll
      for (int c = 0; c < 4; ++c){
        bf16x8 v = *(const bf16x8*)(cb + (js*8 + wc*4 + c)*1024 + l*16);
        acc[c] = __builtin_amdgcn_mfma_f32_32x32x16_bf16(v, pf[js].v, acc[c], 0,0,0);
      }
    }

    __builtin_amdgcn_sched_barrier(0);
    __builtin_amdgcn_s_barrier();      // all reads of buf[cur] done before overwrite
  }

  // epilogue: no cross-wave merge needed (every wave saw all j).
  lsum += __shfl_xor(lsum, 32);
  const float sc = gptr[0] / lsum;
  const int ibase = i64*64 + wq*32;
  #pragma unroll
  for (int c = 0; c < 4; ++c){
    #pragma unroll
    for (int r = 0; r < 16; ++r){
      const int cg = wc*128 + c*32 + (r & 3) + 8*(r >> 2) + 4*h;
      const size_t idx = ((size_t)b*Cn + cg)*Nn + ibase + lo;
      out[idx] = acc[c][r]*sc + x[idx];
    }
  }
}

extern "C" void kernel_launch(void* const* d_in, const int* in_sizes, int n_in,
                              void* d_out, int out_size, void* d_ws, size_t ws_size,
                              hipStream_t stream) {
  const float* x     = (const float*)d_in[0];
  const float* Wq    = (const float*)d_in[1];
  const float* bq    = (const float*)d_in[2];
  const float* Wk    = (const float*)d_in[3];
  const float* bk    = (const float*)d_in[4];
  const float* Wv    = (const float*)d_in[5];
  const float* bv    = (const float*)d_in[6];
  const float* gamma = (const float*)d_in[7];
  float* out = (float*)d_out;

  __hip_bfloat16* Qf = (__hip_bfloat16*)d_ws;          // 16*72*2*512
  __hip_bfloat16* Kf = Qf + (size_t)Bn*72*2*512;
  __hip_bfloat16* Vf = Kf + (size_t)Bn*72*2*512;       // 16*144*8*512
  __hip_bfloat16* Wf = Vf + (size_t)Bn*144*8*512;      // 17*10*512

  wfrag_kernel<<<dim3(170), dim3(64), 0, stream>>>(Wq, bq, Wk, bk, Wv, bv, Wf);
  proj_kernel<<<dim3(288), dim3(256), 0, stream>>>(x, Wf, Qf, Kf, Vf);
  attn_kernel<<<dim3(576), dim3(256), 0, stream>>>(Qf, Kf, Vf, x, gamma, out);
}

// Round 7
// 150.052 us; speedup vs baseline: 1.1986x; 1.1986x over previous
//
#include <hip/hip_runtime.h>
#include <hip/hip_bf16.h>

#define Bn  16
#define Cn  256
#define CKn 32
#define Nn  2304   // 48*48

typedef __attribute__((ext_vector_type(16))) float f32x16;
typedef __attribute__((ext_vector_type(8)))  short bf16x8;

union FragU { unsigned u[4]; bf16x8 v; };

__device__ __forceinline__ unsigned pk(float lo, float hi){
  unsigned a = (unsigned)__bfloat16_as_ushort(__float2bfloat16(lo));
  unsigned b = (unsigned)__bfloat16_as_ushort(__float2bfloat16(hi));
  return a | (b << 16);
}

// D-layout (col=lane&31, row=(r&3)+8*(r>>2)+4h) -> A/B-frag layout (row/col=lane&31,
// k=8h+e). Outputs: w0 (k-pair 16kt+8h), w2 (k-pair 16kt+8h+4).
__device__ __forceinline__ void halfswap(unsigned A, unsigned Bv, int h,
                                         unsigned &w0, unsigned &w2){
  unsigned As = (unsigned)__shfl_xor((int)A, 32);
  unsigned Bs = (unsigned)__shfl_xor((int)Bv, 32);
  w0 = h ? Bs : A;
  w2 = h ? Bv : As;
}

__device__ __forceinline__ void conv_store(const f32x16& a, int h, int l,
                                           __hip_bfloat16* dst0, size_t stride){
  unsigned Wp[8];
  #pragma unroll
  for (int q = 0; q < 8; ++q) Wp[q] = pk(a[2*q], a[2*q+1]);
  #pragma unroll
  for (int k2 = 0; k2 < 2; ++k2){
    FragU u;
    halfswap(Wp[4*k2+0], Wp[4*k2+2], h, u.u[0], u.u[2]);
    halfswap(Wp[4*k2+1], Wp[4*k2+3], h, u.u[1], u.u[3]);
    *(bf16x8*)(dst0 + k2*stride + l*8) = u.v;
  }
}

// async global -> LDS, 16B per lane; LDS dest is wave-uniform base + lane*16
__device__ __forceinline__ void gld16(const void* g, void* l){
  __builtin_amdgcn_global_load_lds(
      (__attribute__((address_space(1))) void*)const_cast<void*>(g),
      (__attribute__((address_space(3))) void*)l, 16, 0, 0);
}

// ---------------------------------------------------------------------------
// Pack weights+bias into MFMA frag layout. Wf[kt 0..16][tile 0..9][512] bf16.
// ---------------------------------------------------------------------------
__global__ __launch_bounds__(64) void wfrag_kernel(
    const float* __restrict__ Wq, const float* __restrict__ bq,
    const float* __restrict__ Wk, const float* __restrict__ bk,
    const float* __restrict__ Wv, const float* __restrict__ bv,
    __hip_bfloat16* __restrict__ Wf){
  const int kt = blockIdx.x / 10, tile = blockIdx.x % 10;
  const int l = threadIdx.x, lo = l & 31, h = l >> 5;
  __hip_bfloat16* dst = Wf + (size_t)(kt*10 + tile)*512 + l*8;
  if (kt < 16){
    const float* Wp; int row;
    if (tile < 8)       { Wp = Wv; row = tile*32 + lo; }
    else if (tile == 8) { Wp = Wq; row = lo; }
    else                { Wp = Wk; row = lo; }
    #pragma unroll
    for (int e = 0; e < 8; ++e)
      dst[e] = __float2bfloat16(Wp[(size_t)row*Cn + kt*16 + 8*h + e]);
  } else {
    const float* bp = tile < 8 ? bv : (tile == 8 ? bq : bk);
    int row = tile < 8 ? tile*32 + lo : lo;
    #pragma unroll
    for (int e = 0; e < 8; ++e)
      dst[e] = __float2bfloat16((h == 0 && e == 0) ? bp[row] : 0.f);
  }
}

// ---------------------------------------------------------------------------
// Projection GEMM. Q is pre-scaled by log2(e)/sqrt(C).
// ---------------------------------------------------------------------------
__global__ __launch_bounds__(256) void proj_kernel(
    const float* __restrict__ x, const __hip_bfloat16* __restrict__ Wf,
    __hip_bfloat16* __restrict__ Qf, __hip_bfloat16* __restrict__ Kf,
    __hip_bfloat16* __restrict__ Vf){
  const int u = blockIdx.x*4 + (threadIdx.x >> 6);
  const int b = u / 72, n32 = u % 72;
  const int l = threadIdx.x & 63, lo = l & 31, h = l >> 5;
  const int n0 = n32*32;

  f32x16 acc[10];
  #pragma unroll
  for (int t = 0; t < 10; ++t)
    #pragma unroll
    for (int r = 0; r < 16; ++r) acc[t][r] = 0.f;

  const float* xb = x + (size_t)b*Cn*Nn + n0 + lo;

  #pragma unroll 1
  for (int kt = 0; kt < 16; ++kt){
    FragU xf;
    float v[8];
    #pragma unroll
    for (int e = 0; e < 8; ++e) v[e] = xb[(size_t)(kt*16 + 8*h + e)*Nn];
    #pragma unroll
    for (int q = 0; q < 4; ++q) xf.u[q] = pk(v[2*q], v[2*q+1]);
    const __hip_bfloat16* wfp = Wf + (size_t)(kt*10)*512 + l*8;
    #pragma unroll
    for (int t = 0; t < 10; ++t){
      bf16x8 wf = *(const bf16x8*)(wfp + t*512);
      if (t < 8) acc[t] = __builtin_amdgcn_mfma_f32_32x32x16_bf16(xf.v, wf, acc[t], 0,0,0);
      else       acc[t] = __builtin_amdgcn_mfma_f32_32x32x16_bf16(wf, xf.v, acc[t], 0,0,0);
    }
  }
  { // bias k-step
    FragU xf;
    xf.u[0] = h ? 0u : 0x00003f80u;
    xf.u[1] = xf.u[2] = xf.u[3] = 0u;
    const __hip_bfloat16* wfp = Wf + (size_t)(16*10)*512 + l*8;
    #pragma unroll
    for (int t = 0; t < 10; ++t){
      bf16x8 wf = *(const bf16x8*)(wfp + t*512);
      if (t < 8) acc[t] = __builtin_amdgcn_mfma_f32_32x32x16_bf16(xf.v, wf, acc[t], 0,0,0);
      else       acc[t] = __builtin_amdgcn_mfma_f32_32x32x16_bf16(wf, xf.v, acc[t], 0,0,0);
    }
  }

  // fold softmax scale into Q: k1 = log2(e)/sqrt(256)
  #pragma unroll
  for (int r = 0; r < 16; ++r) acc[8][r] *= 0.09016844f;

  #pragma unroll
  for (int t = 0; t < 8; ++t)
    conv_store(acc[t], h, l, Vf + (((size_t)b*144 + n32*2)*8 + t)*512, 8*512);
  conv_store(acc[8], h, l, Qf + ((size_t)b*72 + n32)*2*512, 512);
  conv_store(acc[9], h, l, Kf + ((size_t)b*72 + n32)*2*512, 512);
}

// ---------------------------------------------------------------------------
// Attention: block = (b, 128 q-rows, 128-channel half). 4 waves = 4 disjoint
// 32q slices (no softmax/QK duplication); each wave computes 32q x 128c.
// V(ch-half)+K double-buffered in LDS via global_load_lds, counted vmcnt(5),
// 2-phase barriers. LDS 48KB -> 3 blocks/CU; regs ~152 -> 3 waves/SIMD.
// ---------------------------------------------------------------------------
__global__ __launch_bounds__(256, 3) void attn_kernel(
    const __hip_bfloat16* __restrict__ Qf, const __hip_bfloat16* __restrict__ Kf,
    const __hip_bfloat16* __restrict__ Vf, const float* __restrict__ x,
    const float* __restrict__ gptr, float* __restrict__ out){
  // LDS: V dbuf 2x16K | K dbuf 2x4K @32768 | Q 8K @40960  = 48 KiB
  __shared__ __align__(16) char smem[49152];
  const int xcd = blockIdx.x & 7, seq = blockIdx.x >> 3;   // 576 = 8*72
  const int b    = xcd*2 + (seq / 36);                     // 2 batches per XCD
  const int rem  = seq % 36;
  const int q128 = rem >> 1;                               // 0..17
  const int ch   = rem & 1;                                // channel half
  const int tid = threadIdx.x;
  const int w = tid >> 6, l = tid & 63, lo = l & 31, h = l >> 5;

  // stage one (64j x 128c V-half + 64j x 32d K) tile: 5 uniform rounds
  auto stage = [&](int jt, int buf){
    // V: 4 rounds; round r = j-16-slab r, frag cf = tid>>6 of this ch half
    #pragma unroll
    for (int r = 0; r < 4; ++r){
      const char* gV = (const char*)Vf
          + ((size_t)((b*144 + jt*4 + r)*8 + ch*4 + (tid >> 6)))*1024
          + (size_t)(tid & 63)*16;
      gld16(gV, smem + buf*16384 + r*4096 + w*1024);
    }
    // K: 1 round, exactly 4 KB (64j x 32d bf16)
    const char* gK = (const char*)Kf + ((size_t)(b*72 + jt*2))*2048 + (size_t)tid*16;
    gld16(gK, smem + 32768 + buf*4096 + w*1024);
  };

  // prologue: Q (2 rounds, 8 KB = 128q x 32d) + tile 0, then full drain
  #pragma unroll
  for (int r = 0; r < 2; ++r){
    const char* gQ = (const char*)Qf + ((size_t)(b*72 + q128*4))*2048
                   + r*4096 + (size_t)tid*16;
    gld16(gQ, smem + 40960 + r*4096 + w*1024);
  }
  stage(0, 0);
  asm volatile("s_waitcnt vmcnt(0)" ::: "memory");
  __builtin_amdgcn_s_barrier();
  __builtin_amdgcn_sched_barrier(0);

  // per-wave Q frags: it-tile = q128*4 + w
  bf16x8 qf[2];
  #pragma unroll
  for (int kt = 0; kt < 2; ++kt)
    qf[kt] = *(const bf16x8*)(smem + 40960 + (w*2 + kt)*1024 + l*16);

  f32x16 acc[4];
  #pragma unroll
  for (int c = 0; c < 4; ++c)
    #pragma unroll
    for (int r = 0; r < 16; ++r) acc[c][r] = 0.f;
  float m = -3.0e38f, lsum = 0.f;

  #pragma unroll 1
  for (int jt = 0; jt < 36; ++jt){
    const int cur = jt & 1;
    int jtn = jt + 1; if (jtn == 36) jtn = 0;   // wrap keeps vmcnt uniform
    stage(jtn, cur ^ 1);
    asm volatile("s_waitcnt vmcnt(5)" ::: "memory");  // tile jt landed; jt+1 flying
    __builtin_amdgcn_s_barrier();
    __builtin_amdgcn_sched_barrier(0);

    const char* cbV = smem + cur*16384;
    const char* cbK = smem + 32768 + cur*4096;
    bf16x8 kf[2][2];
    #pragma unroll
    for (int js = 0; js < 2; ++js)
      #pragma unroll
      for (int kt = 0; kt < 2; ++kt)
        kf[js][kt] = *(const bf16x8*)(cbK + (js*2 + kt)*1024 + l*16);

    f32x16 z;
    #pragma unroll
    for (int r = 0; r < 16; ++r) z[r] = 0.f;
    f32x16 S0 = __builtin_amdgcn_mfma_f32_32x32x16_bf16(kf[0][0], qf[0], z, 0,0,0);
    S0 = __builtin_amdgcn_mfma_f32_32x32x16_bf16(kf[0][1], qf[1], S0, 0,0,0);
    f32x16 S1 = __builtin_amdgcn_mfma_f32_32x32x16_bf16(kf[1][0], qf[0], z, 0,0,0);
    S1 = __builtin_amdgcn_mfma_f32_32x32x16_bf16(kf[1][1], qf[1], S1, 0,0,0);

    // tree max (S already in log2 domain via pre-scaled Q)
    float tm[16];
    #pragma unroll
    for (int r = 0; r < 16; ++r) tm[r] = fmaxf(S0[r], S1[r]);
    #pragma unroll
    for (int s = 8; s > 0; s >>= 1)
      #pragma unroll
      for (int r = 0; r < s; ++r) tm[r] = fmaxf(tm[r], tm[r+s]);
    float mloc = fmaxf(tm[0], __shfl_xor(tm[0], 32));
    if (__any(mloc > m + 8.f)){          // defer-max
      float mnew = fmaxf(m, mloc);
      float f = exp2f(m - mnew);
      lsum *= f;
      #pragma unroll
      for (int c = 0; c < 4; ++c)
        #pragma unroll
        for (int r = 0; r < 16; ++r) acc[c][r] *= f;
      m = mnew;
    }

    FragU pf[4];
    float sadd0 = 0.f, sadd1 = 0.f;
    {
      unsigned Wp[8];
      #pragma unroll
      for (int q = 0; q < 8; ++q){
        float p0 = exp2f(S0[2*q]   - m);
        float p1 = exp2f(S0[2*q+1] - m);
        sadd0 += p0 + p1; Wp[q] = pk(p0, p1);
      }
      halfswap(Wp[0], Wp[2], h, pf[0].u[0], pf[0].u[2]);
      halfswap(Wp[1], Wp[3], h, pf[0].u[1], pf[0].u[3]);
      halfswap(Wp[4], Wp[6], h, pf[1].u[0], pf[1].u[2]);
      halfswap(Wp[5], Wp[7], h, pf[1].u[1], pf[1].u[3]);
    }
    {
      unsigned Wp[8];
      #pragma unroll
      for (int q = 0; q < 8; ++q){
        float p0 = exp2f(S1[2*q]   - m);
        float p1 = exp2f(S1[2*q+1] - m);
        sadd1 += p0 + p1; Wp[q] = pk(p0, p1);
      }
      halfswap(Wp[0], Wp[2], h, pf[2].u[0], pf[2].u[2]);
      halfswap(Wp[1], Wp[3], h, pf[2].u[1], pf[2].u[3]);
      halfswap(Wp[4], Wp[6], h, pf[3].u[0], pf[3].u[2]);
      halfswap(Wp[5], Wp[7], h, pf[3].u[1], pf[3].u[3]);
    }
    lsum += sadd0 + sadd1;

    // PV from LDS: 4 c-tiles of this block's 128-channel half
    #pragma unroll
    for (int js = 0; js < 4; ++js){
      #pragma unroll
      for (int c = 0; c < 4; ++c){
        bf16x8 v = *(const bf16x8*)(cbV + (js*4 + c)*1024 + l*16);
        acc[c] = __builtin_amdgcn_mfma_f32_32x32x16_bf16(v, pf[js].v, acc[c], 0,0,0);
      }
    }

    __builtin_amdgcn_sched_barrier(0);
    __builtin_amdgcn_s_barrier();      // buf[cur] reads done before overwrite
  }

  // epilogue: no cross-wave merge (every wave saw all j); direct store
  lsum += __shfl_xor(lsum, 32);
  const float sc = gptr[0] / lsum;
  const int ibase = q128*128 + w*32;
  #pragma unroll
  for (int c = 0; c < 4; ++c){
    #pragma unroll
    for (int r = 0; r < 16; ++r){
      const int cg = ch*128 + c*32 + (r & 3) + 8*(r >> 2) + 4*h;
      const size_t idx = ((size_t)b*Cn + cg)*Nn + ibase + lo;
      out[idx] = acc[c][r]*sc + x[idx];
    }
  }
}

extern "C" void kernel_launch(void* const* d_in, const int* in_sizes, int n_in,
                              void* d_out, int out_size, void* d_ws, size_t ws_size,
                              hipStream_t stream) {
  const float* x     = (const float*)d_in[0];
  const float* Wq    = (const float*)d_in[1];
  const float* bq    = (const float*)d_in[2];
  const float* Wk    = (const float*)d_in[3];
  const float* bk    = (const float*)d_in[4];
  const float* Wv    = (const float*)d_in[5];
  const float* bv    = (const float*)d_in[6];
  const float* gamma = (const float*)d_in[7];
  float* out = (float*)d_out;

  __hip_bfloat16* Qf = (__hip_bfloat16*)d_ws;          // 16*72*2*512
  __hip_bfloat16* Kf = Qf + (size_t)Bn*72*2*512;
  __hip_bfloat16* Vf = Kf + (size_t)Bn*72*2*512;       // 16*144*8*512
  __hip_bfloat16* Wf = Vf + (size_t)Bn*144*8*512;      // 17*10*512

  wfrag_kernel<<<dim3(170), dim3(64), 0, stream>>>(Wq, bq, Wk, bk, Wv, bv, Wf);
  proj_kernel<<<dim3(288), dim3(256), 0, stream>>>(x, Wf, Qf, Kf, Vf);
  attn_kernel<<<dim3(576), dim3(256), 0, stream>>>(Qf, Kf, Vf, x, gamma, out);
}